// Round 3
// baseline (610.551 us; speedup 1.0000x reference)
//
#include <hip/hip_runtime.h>
#include <hip/hip_bf16.h>
#include <math.h>

#define TOKENS 8192
#define IN_F   4096
#define OUT_F  4096
#define LR     16

typedef __bf16 bf16_t;
typedef __attribute__((ext_vector_type(8)))  __bf16 bf16x8;
typedef __attribute__((ext_vector_type(4)))  __bf16 bf16x4;
typedef __attribute__((ext_vector_type(4)))  float  floatx4;
typedef __attribute__((ext_vector_type(16))) float  floatx16;

#define GL2LDS(gp, lp) \
    __builtin_amdgcn_global_load_lds((const __attribute__((address_space(1))) unsigned int*)(gp), \
                                     (__attribute__((address_space(3))) unsigned int*)(lp), 16, 0, 0)

// ---------------- kernel 1: P = A A^T (16x16), Q = B^T B (16x16) ----------------
__global__ void pq_kernel(const float* __restrict__ A, const float* __restrict__ B,
                          float* __restrict__ P, float* __restrict__ Q) {
    __shared__ float red[256];
    const int b = blockIdx.x, t = threadIdx.x;
    float s = 0.f;
    if (b < 256) {
        const int i = b >> 4, j = b & 15;
        const float* ai = A + (size_t)i * IN_F;
        const float* aj = A + (size_t)j * IN_F;
        for (int k = t; k < IN_F; k += 256) s += ai[k] * aj[k];
    } else {
        const int i = (b - 256) >> 4, j = (b - 256) & 15;
        for (int k = t; k < OUT_F; k += 256) s += B[k * LR + i] * B[k * LR + j];
    }
    red[t] = s; __syncthreads();
    for (int off = 128; off > 0; off >>= 1) {
        if (t < off) red[t] += red[t + off];
        __syncthreads();
    }
    if (t == 0) {
        if (b < 256) P[b] = red[0];
        else         Q[b - 256] = red[0];
    }
}

// ---------------- kernel 2: rank-space Newton-Schulz (fp64, 16x16) ----------------
// X_k = B S_k A;  S <- a S + b T S + c T^2 S,  T = S P S^T Q.  Sc = alpha * S_5.
__global__ void ns_kernel(const float* __restrict__ P, const float* __restrict__ Q,
                          float* __restrict__ Sc) {
    __shared__ double Ps[256], Qs[256], Ss[256], Ys[256], Zs[256], Ts[256], Us[256], Vs[256];
    __shared__ double alpha_s, inv_n;
    const int t = threadIdx.x, i = t >> 4, j = t & 15;
    Ps[t] = P[t]; Qs[t] = Q[t];
    __syncthreads();
    if (t == 0) {
        double s = 0.0;
        for (int a = 0; a < 16; ++a)
            for (int b2 = 0; b2 < 16; ++b2) s += Ps[a * 16 + b2] * Qs[b2 * 16 + a];
        const double al = sqrt(s);           // ||G||_F = sqrt(tr(P Q))
        alpha_s = al;
        inv_n   = 1.0 / (al + 1e-7);
    }
    __syncthreads();
    Ss[t] = (i == j) ? inv_n : 0.0;          // S_0 = I / (||G|| + eps)
    __syncthreads();
    const double ca = 3.4445, cb = -4.775, cc = 2.0315;
    for (int step = 0; step < 5; ++step) {
        double s;
        s = 0; for (int q = 0; q < 16; ++q) s += Ss[i*16+q] * Ps[q*16+j]; Ys[t] = s; __syncthreads(); // Y = S P
        s = 0; for (int q = 0; q < 16; ++q) s += Ys[i*16+q] * Ss[j*16+q]; Zs[t] = s; __syncthreads(); // Z = Y S^T
        s = 0; for (int q = 0; q < 16; ++q) s += Zs[i*16+q] * Qs[q*16+j]; Ts[t] = s; __syncthreads(); // T = Z Q
        s = 0; for (int q = 0; q < 16; ++q) s += Ts[i*16+q] * Ss[q*16+j]; Us[t] = s; __syncthreads(); // U = T S
        s = 0; for (int q = 0; q < 16; ++q) s += Ts[i*16+q] * Us[q*16+j]; Vs[t] = s; __syncthreads(); // V = T U
        Ss[t] = ca * Ss[t] + cb * Us[t] + cc * Vs[t];
        __syncthreads();
    }
    Sc[t] = (float)(alpha_s * Ss[t]);
}

// ---------------- kernel 3: ScA[r][i] = sum_q Sc[r][q] * A[q][i]  (16 x 4096) ----------------
__global__ void sca_kernel(const float* __restrict__ Sc, const float* __restrict__ A,
                           float* __restrict__ ScA) {
    const int idx = blockIdx.x * 256 + threadIdx.x;   // 65536 total
    const int r = idx >> 12, i = idx & 4095;
    float s = 0.f;
    for (int q = 0; q < 16; ++q) s += Sc[r * 16 + q] * A[q * IN_F + i];
    ScA[r * IN_F + i] = s;
}

// ---------------- kernel 4: W_eff (bf16) = W + B_lora @ ScA ----------------
__global__ void weff_kernel(const float* __restrict__ W, const float* __restrict__ Bm,
                            const float* __restrict__ ScA, bf16_t* __restrict__ Wb) {
    const int b = blockIdx.x, t = threadIdx.x;
    const int o0 = (b >> 2) * 4;              // 4 output rows per block
    const int i  = (b & 3) * 1024 + t * 4;    // 4 consecutive cols per thread
    float4 acc[4];
    #pragma unroll
    for (int r = 0; r < 4; ++r) acc[r] = *(const float4*)&W[(size_t)(o0 + r) * IN_F + i];
    #pragma unroll
    for (int q = 0; q < LR; ++q) {
        const float4 sa = *(const float4*)&ScA[q * IN_F + i];
        #pragma unroll
        for (int r = 0; r < 4; ++r) {
            const float bq = Bm[(o0 + r) * LR + q];
            acc[r].x += bq * sa.x; acc[r].y += bq * sa.y;
            acc[r].z += bq * sa.z; acc[r].w += bq * sa.w;
        }
    }
    #pragma unroll
    for (int r = 0; r < 4; ++r) {
        bf16x4 v;
        v[0] = (__bf16)acc[r].x; v[1] = (__bf16)acc[r].y;
        v[2] = (__bf16)acc[r].z; v[3] = (__bf16)acc[r].w;
        *(bf16x4*)&Wb[(size_t)(o0 + r) * IN_F + i] = v;
    }
}

// ---------------- kernel 5: x (fp32) -> bf16 ----------------
__global__ void cvtx_kernel(const float* __restrict__ x, bf16_t* __restrict__ Xb) {
    const int idx = blockIdx.x * 256 + threadIdx.x;   // float4 index
    const float4 u = ((const float4*)x)[idx];
    bf16x4 v;
    v[0] = (__bf16)u.x; v[1] = (__bf16)u.y; v[2] = (__bf16)u.z; v[3] = (__bf16)u.w;
    ((bf16x4*)Xb)[idx] = v;
}

// ---------------- kernel 6: C = Xb @ Wb^T + bias  (bf16 MFMA) ----------------
// Round-3 change: 16x16x32 -> 32x32x16 MFMA (m119: pipe ceiling 2495 vs 2176 TF,
// -17% MFMA-pipe cycles, half the MFMA instruction count). Staging + LDS chunk
// swizzle identical to round 2 (bank conflicts stay 0): logical 16B-chunk c of
// row r lives at physical chunk (c + ((r>>1)&3)) & 3.
// 32x32x16 operand layout: A/B lane l holds row/col = l&31, k = (l>>5)*8 + j
// (contiguous 16B). C/D (m74/m101): col = lane&31, row = (reg&3)+8*(reg>>2)+4*(lane>>5).
#define BM 128
#define BN 128
#define BK 32

__global__ __launch_bounds__(256) void gemm_kernel(
        const bf16_t* __restrict__ Xb, const bf16_t* __restrict__ Wb,
        const float* __restrict__ bias, float* __restrict__ out) {
    __shared__ bf16_t lA[BM * BK];   // 8 KB
    __shared__ bf16_t lB[BN * BK];   // 8 KB
    const int t = threadIdx.x;
    const int lane = t & 63, wv = t >> 6;
    const int wm = wv & 1, wn = wv >> 1;           // 2x2 wave grid, 64x64 per wave

    // 8x8 supertile swizzle: 64 M-tiles x 32 N-tiles -> supertile grid 8x4
    const int lin = blockIdx.x;
    const int st = lin >> 6, within = lin & 63;
    const int n_tile = (st & 3) * 8 + (within & 7);
    const int m_tile = (st >> 2) * 8 + (within >> 3);
    const int m0 = m_tile * BM, n0 = n_tile * BN;

    // staging: thread t owns LDS bytes [t*16,t*16+16) = row r0=t>>2 (and r0+64),
    // physical chunk p=t&3; fetch logical chunk c=(p-((r0>>1)&3))&3.
    const int r0s = t >> 2, ps = t & 3;
    const int cs = (ps - ((r0s >> 1) & 3) + 4) & 3;
    const bf16_t* gA0 = Xb + (size_t)(m0 + r0s) * IN_F + cs * 8;
    const bf16_t* gA1 = gA0 + (size_t)64 * IN_F;
    const bf16_t* gB0 = Wb + (size_t)(n0 + r0s) * IN_F + cs * 8;
    const bf16_t* gB1 = gB0 + (size_t)64 * IN_F;
    bf16_t* sA0 = &lA[t * 8];        bf16_t* sA1 = &lA[(t + 256) * 8];
    bf16_t* sB0 = &lB[t * 8];        bf16_t* sB1 = &lB[(t + 256) * 8];

    // fragment addressing: row R = wm*64 + mi*32 + ln; (R>>1)&3 == (ln>>1)&3.
    // logical 16B-chunk for k-step s: cc = s*2 + kg, kg = lane>>5.
    const int ln = lane & 31, kg = lane >> 5;
    const int rot = (ln >> 1) & 3;
    const bf16_t* fA = &lA[(wm * 64 + ln) * BK];
    const bf16_t* fB = &lB[(wn * 64 + ln) * BK];

    floatx16 acc00 = {}, acc01 = {}, acc10 = {}, acc11 = {};

    for (int kt = 0; kt < IN_F / BK; ++kt) {
        const int ko = kt * BK;
        GL2LDS(gA0 + ko, sA0);
        GL2LDS(gA1 + ko, sA1);
        GL2LDS(gB0 + ko, sB0);
        GL2LDS(gB1 + ko, sB1);
        __syncthreads();                           // drains vmcnt, data visible
        #pragma unroll
        for (int s = 0; s < 2; ++s) {
            const int po = ((s * 2 + kg + rot) & 3) * 8;
            const bf16x8 a0 = *(const bf16x8*)(fA + po);
            const bf16x8 a1 = *(const bf16x8*)(fA + 32 * BK + po);
            const bf16x8 b0 = *(const bf16x8*)(fB + po);
            const bf16x8 b1 = *(const bf16x8*)(fB + 32 * BK + po);
            acc00 = __builtin_amdgcn_mfma_f32_32x32x16_bf16(a0, b0, acc00, 0, 0, 0);
            acc01 = __builtin_amdgcn_mfma_f32_32x32x16_bf16(a0, b1, acc01, 0, 0, 0);
            acc10 = __builtin_amdgcn_mfma_f32_32x32x16_bf16(a1, b0, acc10, 0, 0, 0);
            acc11 = __builtin_amdgcn_mfma_f32_32x32x16_bf16(a1, b1, acc11, 0, 0, 0);
        }
        __syncthreads();                           // all reads done before next overwrite
    }

    // C/D layout (m74/m101): col = lane&31, row = (reg&3) + 8*(reg>>2) + 4*kg
    const int colb = n0 + wn * 64 + ln;
    const int rowb = m0 + wm * 64 + 4 * kg;
    const float bv0 = bias[colb];
    const float bv1 = bias[colb + 32];
    #pragma unroll
    for (int rg = 0; rg < 16; ++rg) {
        const int row = rowb + (rg & 3) + 8 * (rg >> 2);
        out[(size_t)row * OUT_F + colb]             = acc00[rg] + bv0;
        out[(size_t)row * OUT_F + colb + 32]        = acc01[rg] + bv1;
        out[(size_t)(row + 32) * OUT_F + colb]      = acc10[rg] + bv0;
        out[(size_t)(row + 32) * OUT_F + colb + 32] = acc11[rg] + bv1;
    }
}

extern "C" void kernel_launch(void* const* d_in, const int* in_sizes, int n_in,
                              void* d_out, int out_size, void* d_ws, size_t ws_size,
                              hipStream_t stream) {
    const float* x    = (const float*)d_in[0];
    const float* W    = (const float*)d_in[1];
    const float* bias = (const float*)d_in[2];
    const float* lA_  = (const float*)d_in[3];
    const float* lB_  = (const float*)d_in[4];
    float* out = (float*)d_out;

    // workspace layout (~101 MB)
    char* ws = (char*)d_ws;
    bf16_t* Xb  = (bf16_t*)ws;                               // 8192*4096*2 = 67108864
    bf16_t* Wb  = (bf16_t*)(ws + 67108864);                  // 4096*4096*2 = 33554432
    float*  ScA = (float*)(ws + 100663296);                  // 16*4096*4   = 262144
    float*  P   = (float*)(ws + 100925440);                  // 256 floats
    float*  Q   = P + 256;
    float*  Sc  = Q + 256;

    pq_kernel  <<<512, 256, 0, stream>>>(lA_, lB_, P, Q);
    ns_kernel  <<<1, 256, 0, stream>>>(P, Q, Sc);
    sca_kernel <<<256, 256, 0, stream>>>(Sc, lA_, ScA);
    weff_kernel<<<4096, 256, 0, stream>>>(W, lB_, ScA, Wb);
    cvtx_kernel<<<TOKENS * IN_F / 4 / 256, 256, 0, stream>>>(x, Xb);
    gemm_kernel<<<2048, 256, 0, stream>>>(Xb, Wb, bias, out);
}

// Round 4
// 576.068 us; speedup vs baseline: 1.0599x; 1.0599x over previous
//
#include <hip/hip_runtime.h>
#include <hip/hip_bf16.h>
#include <math.h>

#define TOKENS 8192
#define IN_F   4096
#define OUT_F  4096
#define LR     16

typedef __bf16 bf16_t;
typedef __attribute__((ext_vector_type(8)))  __bf16 bf16x8;
typedef __attribute__((ext_vector_type(4)))  __bf16 bf16x4;
typedef __attribute__((ext_vector_type(4)))  float  floatx4;
typedef __attribute__((ext_vector_type(16))) float  floatx16;

#define GL2LDS(gp, lp) \
    __builtin_amdgcn_global_load_lds((const __attribute__((address_space(1))) unsigned int*)(gp), \
                                     (__attribute__((address_space(3))) unsigned int*)(lp), 16, 0, 0)

// ---------------- kernel 1: P = A A^T (16x16), Q = B^T B (16x16) ----------------
__global__ void pq_kernel(const float* __restrict__ A, const float* __restrict__ B,
                          float* __restrict__ P, float* __restrict__ Q) {
    __shared__ float red[256];
    const int b = blockIdx.x, t = threadIdx.x;
    float s = 0.f;
    if (b < 256) {
        const int i = b >> 4, j = b & 15;
        const float* ai = A + (size_t)i * IN_F;
        const float* aj = A + (size_t)j * IN_F;
        for (int k = t; k < IN_F; k += 256) s += ai[k] * aj[k];
    } else {
        const int i = (b - 256) >> 4, j = (b - 256) & 15;
        for (int k = t; k < OUT_F; k += 256) s += B[k * LR + i] * B[k * LR + j];
    }
    red[t] = s; __syncthreads();
    for (int off = 128; off > 0; off >>= 1) {
        if (t < off) red[t] += red[t + off];
        __syncthreads();
    }
    if (t == 0) {
        if (b < 256) P[b] = red[0];
        else         Q[b - 256] = red[0];
    }
}

// ---------------- kernel 2: rank-space Newton-Schulz (fp64, 16x16) ----------------
// X_k = B S_k A;  S <- a S + b T S + c T^2 S,  T = S P S^T Q.  Sc = alpha * S_5.
__global__ void ns_kernel(const float* __restrict__ P, const float* __restrict__ Q,
                          float* __restrict__ Sc) {
    __shared__ double Ps[256], Qs[256], Ss[256], Ys[256], Zs[256], Ts[256], Us[256], Vs[256];
    __shared__ double alpha_s, inv_n;
    const int t = threadIdx.x, i = t >> 4, j = t & 15;
    Ps[t] = P[t]; Qs[t] = Q[t];
    __syncthreads();
    if (t == 0) {
        double s = 0.0;
        for (int a = 0; a < 16; ++a)
            for (int b2 = 0; b2 < 16; ++b2) s += Ps[a * 16 + b2] * Qs[b2 * 16 + a];
        const double al = sqrt(s);           // ||G||_F = sqrt(tr(P Q))
        alpha_s = al;
        inv_n   = 1.0 / (al + 1e-7);
    }
    __syncthreads();
    Ss[t] = (i == j) ? inv_n : 0.0;          // S_0 = I / (||G|| + eps)
    __syncthreads();
    const double ca = 3.4445, cb = -4.775, cc = 2.0315;
    for (int step = 0; step < 5; ++step) {
        double s;
        s = 0; for (int q = 0; q < 16; ++q) s += Ss[i*16+q] * Ps[q*16+j]; Ys[t] = s; __syncthreads(); // Y = S P
        s = 0; for (int q = 0; q < 16; ++q) s += Ys[i*16+q] * Ss[j*16+q]; Zs[t] = s; __syncthreads(); // Z = Y S^T
        s = 0; for (int q = 0; q < 16; ++q) s += Zs[i*16+q] * Qs[q*16+j]; Ts[t] = s; __syncthreads(); // T = Z Q
        s = 0; for (int q = 0; q < 16; ++q) s += Ts[i*16+q] * Ss[q*16+j]; Us[t] = s; __syncthreads(); // U = T S
        s = 0; for (int q = 0; q < 16; ++q) s += Ts[i*16+q] * Us[q*16+j]; Vs[t] = s; __syncthreads(); // V = T U
        Ss[t] = ca * Ss[t] + cb * Us[t] + cc * Vs[t];
        __syncthreads();
    }
    Sc[t] = (float)(alpha_s * Ss[t]);
}

// ---------------- kernel 3: ScA[r][i] = sum_q Sc[r][q] * A[q][i]  (16 x 4096) ----------------
__global__ void sca_kernel(const float* __restrict__ Sc, const float* __restrict__ A,
                           float* __restrict__ ScA) {
    const int idx = blockIdx.x * 256 + threadIdx.x;   // 65536 total
    const int r = idx >> 12, i = idx & 4095;
    float s = 0.f;
    for (int q = 0; q < 16; ++q) s += Sc[r * 16 + q] * A[q * IN_F + i];
    ScA[r * IN_F + i] = s;
}

// ---------------- kernel 4 (fused): x->bf16 convert  +  W_eff = W + B@ScA (bf16) ----
// blocks [0, 32768): cvtx; blocks [32768, 36864): weff.  Both memory-bound; fusing
// overlaps their HBM streams and saves a launch.
__global__ void prep_kernel(const float* __restrict__ x, bf16_t* __restrict__ Xb,
                            const float* __restrict__ W, const float* __restrict__ Bm,
                            const float* __restrict__ ScA, bf16_t* __restrict__ Wb) {
    const int b = blockIdx.x, t = threadIdx.x;
    if (b < 32768) {
        const int idx = b * 256 + t;                  // float4 index
        const float4 u = ((const float4*)x)[idx];
        bf16x4 v;
        v[0] = (__bf16)u.x; v[1] = (__bf16)u.y; v[2] = (__bf16)u.z; v[3] = (__bf16)u.w;
        ((bf16x4*)Xb)[idx] = v;
        return;
    }
    const int bb = b - 32768;
    const int o0 = (bb >> 2) * 4;             // 4 output rows per block
    const int i  = (bb & 3) * 1024 + t * 4;   // 4 consecutive cols per thread
    float4 acc[4];
    #pragma unroll
    for (int r = 0; r < 4; ++r) acc[r] = *(const float4*)&W[(size_t)(o0 + r) * IN_F + i];
    #pragma unroll
    for (int q = 0; q < LR; ++q) {
        const float4 sa = *(const float4*)&ScA[q * IN_F + i];
        #pragma unroll
        for (int r = 0; r < 4; ++r) {
            const float bq = Bm[(o0 + r) * LR + q];
            acc[r].x += bq * sa.x; acc[r].y += bq * sa.y;
            acc[r].z += bq * sa.z; acc[r].w += bq * sa.w;
        }
    }
    #pragma unroll
    for (int r = 0; r < 4; ++r) {
        bf16x4 v;
        v[0] = (__bf16)acc[r].x; v[1] = (__bf16)acc[r].y;
        v[2] = (__bf16)acc[r].z; v[3] = (__bf16)acc[r].w;
        *(bf16x4*)&Wb[(size_t)(o0 + r) * IN_F + i] = v;
    }
}

// ---------------- kernel 5: C = Xb @ Wb^T + bias  (bf16 32x32x16 MFMA, BK=64) ----
// Round-4 change: BK 32 -> 64 (32 KB LDS, occupancy still reg-limited ~3 blk/CU).
// Halves barrier count; each vmcnt(0) drain amortized over 2x compute.
// 8-ary LDS chunk swizzle for 128B rows: logical 16B-chunk c of row r stored at
// physical chunk (c + (r&7)) & 7.  Fragment rows differ from ln only by mults of
// 32, so rotation = (ln&7): any 8 consecutive lanes hit all 32 banks once.
#define BM 128
#define BN 128
#define BK 64

__global__ __launch_bounds__(256) void gemm_kernel(
        const bf16_t* __restrict__ Xb, const bf16_t* __restrict__ Wb,
        const float* __restrict__ bias, float* __restrict__ out) {
    __shared__ bf16_t lA[BM * BK];   // 16 KB
    __shared__ bf16_t lB[BN * BK];   // 16 KB
    const int t = threadIdx.x;
    const int lane = t & 63, wv = t >> 6;
    const int wm = wv & 1, wn = wv >> 1;           // 2x2 wave grid, 64x64 per wave

    // 8x8 supertile swizzle: 64 M-tiles x 32 N-tiles -> supertile grid 8x4
    const int lin = blockIdx.x;
    const int st = lin >> 6, within = lin & 63;
    const int n_tile = (st & 3) * 8 + (within & 7);
    const int m_tile = (st >> 2) * 8 + (within >> 3);
    const int m0 = m_tile * BM, n0 = n_tile * BN;

    // staging: chunk id (j*256 + t) = row r*8 + phys p, r = j*32 + (t>>3), p = t&7.
    // fetch logical chunk c = (p - (r&7)) & 7  (j-independent since j*32 ≡ 0 mod 8).
    const int rsub = t >> 3;
    const int cs = ((t & 7) - (rsub & 7) + 8) & 7;
    const bf16_t* gA = Xb + (size_t)(m0 + rsub) * IN_F + cs * 8;
    const bf16_t* gB = Wb + (size_t)(n0 + rsub) * IN_F + cs * 8;

    // fragment addressing: row R = wm*64 + {0,32} + ln; R&7 == ln&7.
    // k-step s, half kg: logical chunk cc = s*2 + kg -> phys ((cc + (ln&7)) & 7).
    const int ln = lane & 31, kg = lane >> 5;
    const int rot = ln & 7;
    const bf16_t* fA = &lA[(wm * 64 + ln) * BK];
    const bf16_t* fB = &lB[(wn * 64 + ln) * BK];

    floatx16 acc00 = {}, acc01 = {}, acc10 = {}, acc11 = {};

    for (int kt = 0; kt < IN_F / BK; ++kt) {
        const int ko = kt * BK;
        #pragma unroll
        for (int j = 0; j < 4; ++j)
            GL2LDS(gA + ko + (size_t)j * 32 * IN_F, &lA[j * 2048 + t * 8]);
        #pragma unroll
        for (int j = 0; j < 4; ++j)
            GL2LDS(gB + ko + (size_t)j * 32 * IN_F, &lB[j * 2048 + t * 8]);
        __syncthreads();                           // drains vmcnt, data visible
        #pragma unroll
        for (int s = 0; s < 4; ++s) {
            const int po = ((s * 2 + kg + rot) & 7) * 8;
            const bf16x8 a0 = *(const bf16x8*)(fA + po);
            const bf16x8 a1 = *(const bf16x8*)(fA + 32 * BK + po);
            const bf16x8 b0 = *(const bf16x8*)(fB + po);
            const bf16x8 b1 = *(const bf16x8*)(fB + 32 * BK + po);
            acc00 = __builtin_amdgcn_mfma_f32_32x32x16_bf16(a0, b0, acc00, 0, 0, 0);
            acc01 = __builtin_amdgcn_mfma_f32_32x32x16_bf16(a0, b1, acc01, 0, 0, 0);
            acc10 = __builtin_amdgcn_mfma_f32_32x32x16_bf16(a1, b0, acc10, 0, 0, 0);
            acc11 = __builtin_amdgcn_mfma_f32_32x32x16_bf16(a1, b1, acc11, 0, 0, 0);
        }
        __syncthreads();                           // all reads done before next overwrite
    }

    // C/D layout (m74/m101): col = lane&31, row = (reg&3) + 8*(reg>>2) + 4*kg
    const int colb = n0 + wn * 64 + ln;
    const int rowb = m0 + wm * 64 + 4 * kg;
    const float bv0 = bias[colb];
    const float bv1 = bias[colb + 32];
    #pragma unroll
    for (int rg = 0; rg < 16; ++rg) {
        const int row = rowb + (rg & 3) + 8 * (rg >> 2);
        out[(size_t)row * OUT_F + colb]             = acc00[rg] + bv0;
        out[(size_t)row * OUT_F + colb + 32]        = acc01[rg] + bv1;
        out[(size_t)(row + 32) * OUT_F + colb]      = acc10[rg] + bv0;
        out[(size_t)(row + 32) * OUT_F + colb + 32] = acc11[rg] + bv1;
    }
}

extern "C" void kernel_launch(void* const* d_in, const int* in_sizes, int n_in,
                              void* d_out, int out_size, void* d_ws, size_t ws_size,
                              hipStream_t stream) {
    const float* x    = (const float*)d_in[0];
    const float* W    = (const float*)d_in[1];
    const float* bias = (const float*)d_in[2];
    const float* lA_  = (const float*)d_in[3];
    const float* lB_  = (const float*)d_in[4];
    float* out = (float*)d_out;

    // workspace layout (~101 MB)
    char* ws = (char*)d_ws;
    bf16_t* Xb  = (bf16_t*)ws;                               // 8192*4096*2 = 67108864
    bf16_t* Wb  = (bf16_t*)(ws + 67108864);                  // 4096*4096*2 = 33554432
    float*  ScA = (float*)(ws + 100663296);                  // 16*4096*4   = 262144
    float*  P   = (float*)(ws + 100925440);                  // 256 floats
    float*  Q   = P + 256;
    float*  Sc  = Q + 256;

    pq_kernel  <<<512, 256, 0, stream>>>(lA_, lB_, P, Q);
    ns_kernel  <<<1, 256, 0, stream>>>(P, Q, Sc);
    sca_kernel <<<256, 256, 0, stream>>>(Sc, lA_, ScA);
    prep_kernel<<<36864, 256, 0, stream>>>(x, Xb, W, lB_, ScA, Wb);
    gemm_kernel<<<2048, 256, 0, stream>>>(Xb, Wb, bias, out);
}